// Round 2
// baseline (103.476 us; speedup 1.0000x reference)
//
#include <hip/hip_runtime.h>

// out[n, mu, mup] = sum_{m1+m2==mu+4} sum_{m1p+m2p==mup+4}
//     C[m1,m2]*C[m1p,m2p] * X1[n,m1,m1p] * X2[n,m2,m2p]
//
// R17 == R16 resubmitted (R16 bench died to container infra failure, no
// counters; kernel audited clean: LDS/global bounds, uniform barriers,
// const-indexed register arrays, graph-capture-safe launch).
//
// R16: multi-mu waves + T-factorization + coalesced stores.
//  - Block = 192 threads (3 waves), tile = 64 n (lane = local n).
//  - Wave w owns mu ∈ {w, w+3, w+6} (pairs 20/21/20 — balanced).
//  - m2 outermost (rolled, runtime): build T[q] = w0[q]*x2row[m2p[q]] ONCE
//    per m2, reuse across the wave's (up to 3) m1's -> inner term = 1 FMA.
//    VALU/n: 7991 -> ~5900; LDS reads/n: 1098 -> ~790.
//  - q-enumeration reordered a-major (qsrc[] maps back to the harness's
//    mu-major mult[] order) so consecutive FMAs hit different acc regs
//    (breaks 4-cyc dependent chains).
//  - Stores: acc -> x1s (compute done, buffer reusable) -> lane-contiguous
//    float4 stores. Replaces 81 scattered global_store_dword per block.
//  - Staging path is R15-verbatim (async global_load_lds, width 16),
//    redistributed over 3 waves (42 wave-chunks).
// HARD RULES kept: w0[61] inline SGPR, const-indexed only; T/acc/x2r/x1w
// only ever indexed by unrolled compile-time constants.

namespace {

// a-major enumeration of the 61 valid (m1p=a, m2p=b, mup) q-terms.
// qsrc[q] = index of this term in the harness's mu-major mult[] layout.
struct QTab {
  int m1p[61];
  int m2p[61];
  int mup[61];
  int qsrc[61];
  constexpr QTab() : m1p{}, m2p{}, mup{}, qsrc{} {
    int pre[9] = {0, 5, 11, 18, 26, 35, 43, 50, 56};
    int idx = 0;
    for (int a = 0; a < 9; ++a)
      for (int mu = 0; mu < 9; ++mu) {
        int b = mu + 4 - a;
        if (b >= 0 && b < 9) {
          int alo = (mu - 4 > 0) ? (mu - 4) : 0;
          m1p[idx] = a; m2p[idx] = b; mup[idx] = mu;
          qsrc[idx] = pre[mu] + (a - alo);
          ++idx;
        }
      }
  }
};
constexpr QTab QT{};

}  // namespace

// pairs per mu: [5,6,7,8,9,8,7,6,5]; prefix = first pair index of each mu
__constant__ __device__ int kPrefix[9] = {0, 5, 11, 18, 26, 35, 43, 50, 56};

__device__ __forceinline__ float uniform_f32(float v) {
  return __int_as_float(__builtin_amdgcn_readfirstlane(__float_as_int(v)));
}

typedef unsigned int u32;

// Async global->LDS DMA. Per-lane global src; LDS dest = uniform base +
// lane*SZ. Counts in vmcnt; drained by __syncthreads.
__device__ __forceinline__ void glds16(const float* g, float* lds) {
  __builtin_amdgcn_global_load_lds(
      (const __attribute__((address_space(1))) u32*)g,
      (__attribute__((address_space(3))) u32*)(u32)(uintptr_t)lds, 16, 0, 0);
}
__device__ __forceinline__ void glds4(const float* g, float* lds) {
  __builtin_amdgcn_global_load_lds(
      (const __attribute__((address_space(1))) u32*)g,
      (__attribute__((address_space(3))) u32*)(u32)(uintptr_t)lds, 4, 0, 0);
}

#define NB 64            // n per block
#define NT 192           // threads = 3 waves; wave w owns mu ∈ {w,w+3,w+6}
#define AD (NB * 81)     // 5184 dwords per array per block
#define CH 256           // dwords per x16 wave-chunk (64 lanes * 4 dw)
#define NCH 20           // full x16 chunks per array (20*256 = 5120)
#define TAILB 5120       // tail base (64 dwords, staged at width 4)

__global__ __launch_bounds__(NT)
void wigner_combine_kernel(const float* __restrict__ X1,
                           const float* __restrict__ X2,
                           const float* __restrict__ mult,
                           float* __restrict__ out, int N) {
  __shared__ __align__(16) float x1s[AD];  // 20736 B, linear [n][81]
  __shared__ __align__(16) float x2s[AD];  // 20736 B
  __shared__ float csh[61];                // per-pair scales c_p/c_0

  const int t = threadIdx.x;
  const int w = __builtin_amdgcn_readfirstlane(t >> 6);  // wave id 0..2
  const int lane = t & 63;
  const long gbase = (long)blockIdx.x * AD;  // dword base of this block
  const long totaldw = (long)N * 81;

  // ---- weight row 0 -> 61 SGPRs (inline, constant indices ONLY).
  // w0[q] = c0*c_q for OUR q-order via the compile-time qsrc[] remap.
  float w0[61];
#pragma unroll
  for (int q = 0; q < 61; ++q) w0[q] = uniform_f32(mult[QT.qsrc[q]]);

  if (t < 61) csh[t] = mult[t] * (1.0f / mult[0]);

  // ---- stage: async linear DMA, both arrays. 40 x16 chunks + 2 x4 tails
  // distributed over 3 waves (i = w + 3k covers 0..41 bijectively).
#pragma unroll
  for (int k = 0; k < 14; ++k) {
    const int i = w + 3 * k;  // wave-uniform chunk id
    if (i < 2 * NCH) {
      const int cbase = (i < NCH ? i : i - NCH) * CH;
      const float* gsrc = (i < NCH ? X1 : X2) + gbase + cbase + lane * 4;
      float* ldst = (i < NCH ? x1s : x2s) + cbase;
      if (gbase + cbase + lane * 4 < totaldw) glds16(gsrc, ldst);
    } else if (i == 2 * NCH) {
      if (gbase + TAILB + lane < totaldw)
        glds4(X1 + gbase + TAILB + lane, x1s + TAILB);
    } else if (i == 2 * NCH + 1) {
      if (gbase + TAILB + lane < totaldw)
        glds4(X2 + gbase + TAILB + lane, x2s + TAILB);
    }
  }
  __syncthreads();  // vmcnt(0) drains the DMA

  // ---- compute: wave w handles mu = w, w+3, w+6 for lane's n ----
  const float* __restrict__ lx1 = x1s + lane * 81;
  const float* __restrict__ lx2 = x2s + lane * 81;

  float acc[3][9];
#pragma unroll
  for (int j = 0; j < 3; ++j)
#pragma unroll
    for (int r = 0; r < 9; ++r) acc[j][r] = 0.0f;

#pragma unroll 1  // keep hot loop ~2.5 KB; all 3 waves share this path
  for (int m2 = 0; m2 < 9; ++m2) {
    float x2r[9];
#pragma unroll
    for (int d = 0; d < 9; ++d) x2r[d] = lx2[m2 * 9 + d];

    // T[q] = c0*c_q * X2[n, m2, m2p[q]] — built once, used by up to 3 m1's
    float T[61];
#pragma unroll
    for (int q = 0; q < 61; ++q) T[q] = w0[q] * x2r[QT.m2p[q]];

#pragma unroll
    for (int j = 0; j < 3; ++j) {
      const int mu = w + 3 * j;            // wave-uniform scalar
      const int m1 = mu + 4 - m2;
      if ((unsigned)m1 > 8u) continue;     // uniform guard (scalar branch)
      const int m1lo = (mu - 4 > 0) ? mu - 4 : 0;
      const float sp = csh[kPrefix[mu] + (m1 - m1lo)];  // c_p/c0, broadcast

      float x1w[9];
#pragma unroll
      for (int b = 0; b < 9; ++b) x1w[b] = lx1[m1 * 9 + b] * sp;

      // term = (c_p/c0 * X1) * (c0*c_q * X2): ONE fma per term.
      // a-major order -> consecutive q hit different acc[j][mup] (no chains)
#pragma unroll
      for (int q = 0; q < 61; ++q)
        acc[j][QT.mup[q]] = fmaf(x1w[QT.m1p[q]], T[q], acc[j][QT.mup[q]]);
    }
  }

  // ---- coalesced stores: acc -> x1s (out-tile layout) -> float4 stores ----
  __syncthreads();  // all compute reads of x1s/x2s are done
  {
    float* ob = x1s + lane * 81;
#pragma unroll
    for (int j = 0; j < 3; ++j) {
      const int mu = w + 3 * j;
#pragma unroll
      for (int r = 0; r < 9; ++r) ob[mu * 9 + r] = acc[j][r];
    }
  }
  __syncthreads();

#pragma unroll
  for (int c = 0; c < 7; ++c) {
    const int idx = c * (NT * 4) + t * 4;  // lane-contiguous 16B chunks
    if (idx < AD) {
      const long g = gbase + idx;
      if (g + 4 <= totaldw) {
        *(float4*)(out + g) = *(const float4*)(x1s + idx);
      } else {
#pragma unroll
        for (int u = 0; u < 4; ++u)
          if (g + u < totaldw) out[g + u] = x1s[idx + u];
      }
    }
  }
}

extern "C" void kernel_launch(void* const* d_in, const int* in_sizes, int n_in,
                              void* d_out, int out_size, void* d_ws, size_t ws_size,
                              hipStream_t stream) {
  const float* X1 = (const float*)d_in[0];
  const float* X2 = (const float*)d_in[1];
  const float* mult = (const float*)d_in[6];
  float* out = (float*)d_out;

  const int N = in_sizes[0] / 81;
  const int blocks = (N + NB - 1) / NB;
  wigner_combine_kernel<<<blocks, NT, 0, stream>>>(X1, X2, mult, out, N);
}